// Round 7
// baseline (404.712 us; speedup 1.0000x reference)
//
#include <hip/hip_runtime.h>

#define NN 100000
#define NE 1600000
#define NG 512
#define HD 128

#define NBK 196            // node buckets of 512: 196*512 = 100352 >= NN
#define NB2 392            // dst buckets [0,196) then src buckets [196,392)
#define CHUNK2 2560        // edges per chunk
#define NC2 625            // NE / CHUNK2 exactly

typedef _Float16 h8 __attribute__((ext_vector_type(8)));
typedef float f32x4 __attribute__((ext_vector_type(4)));

// ---------------- build pass 1: per-chunk 392-bucket histogram -> global totals ----
// blocks [0, NC2): edge chunks; blocks [NC2, NC2+48): cast W0..W2 -> Bt (fp16, T)
__global__ __launch_bounds__(1024) void k_count(const int* __restrict__ src,
                                                const int* __restrict__ dst,
                                                int* __restrict__ Btot,
                                                const float* __restrict__ W0,
                                                const float* __restrict__ W1,
                                                const float* __restrict__ W2,
                                                _Float16* __restrict__ Bt) {
    if (blockIdx.x >= NC2) {
        int i = (blockIdx.x - NC2) * 1024 + threadIdx.x;  // < 3*16384 = 48*1024
        int w = i >> 14;
        int rem = i & 16383;
        int n = rem >> 7;
        int k = rem & 127;
        const float* W = (w == 0) ? W0 : ((w == 1) ? W1 : W2);
        Bt[i] = (_Float16)W[k * 128 + n];
        return;
    }
    __shared__ int cnt[NB2];
    int t = threadIdx.x;
    if (t < NB2) cnt[t] = 0;
    __syncthreads();
    int e0 = blockIdx.x * CHUNK2;
    int e1 = e0 + CHUNK2; if (e1 > NE) e1 = NE;
    for (int e = e0 + t; e < e1; e += 1024) {
        atomicAdd(&cnt[dst[e] >> 9], 1);
        atomicAdd(&cnt[NBK + (src[e] >> 9)], 1);
    }
    __syncthreads();
    if (t < NB2 && cnt[t]) atomicAdd(&Btot[t], cnt[t]);  // 392 low-contention atomics
}

// ---------------- build pass 2: scan 392 totals -> base[393]; init cursors ----------
__global__ __launch_bounds__(512) void k_base(const int* __restrict__ Btot,
                                              int* __restrict__ base,
                                              int* __restrict__ gcur) {
    __shared__ int tmp[512];
    int t = threadIdx.x;
    int v = (t < NB2) ? Btot[t] : 0;
    tmp[t] = v;
    __syncthreads();
    for (int off = 1; off < 512; off <<= 1) {
        int v2 = (t >= off) ? tmp[t - off] : 0;
        __syncthreads();
        tmp[t] += v2;
        __syncthreads();
    }
    int ex = tmp[t] - v;
    if (t < NB2) {
        base[t] = ex;
        gcur[t] = ex;
    }
    if (t == 511) base[NB2] = tmp[511];  // = 2*NE
}

// ---------------- build pass 3: partition edges (dynamic per-bucket range claims) ----
// dpart packed: src | (dst&511)<<17  (src < 2^17); spart: src&511 as ushort.
// Phase A: LDS count this chunk. Claim contiguous ranges via global atomicAdd.
// Phase B: re-read chunk (L2-warm) and scatter via LDS cursors. Order within a
// bucket is claim-order (nondeterministic) — harmless, aggregation is a sum.
__global__ __launch_bounds__(1024) void k_scatter2(const int* __restrict__ src,
                                                   const int* __restrict__ dst,
                                                   int* __restrict__ gcur,
                                                   int* __restrict__ dpart,
                                                   unsigned short* __restrict__ spart) {
    __shared__ int cnt[NB2], cur[NB2];
    int t = threadIdx.x;
    if (t < NB2) cnt[t] = 0;
    __syncthreads();
    int e0 = blockIdx.x * CHUNK2;
    int e1 = e0 + CHUNK2; if (e1 > NE) e1 = NE;
    for (int e = e0 + t; e < e1; e += 1024) {
        atomicAdd(&cnt[dst[e] >> 9], 1);
        atomicAdd(&cnt[NBK + (src[e] >> 9)], 1);
    }
    __syncthreads();
    if (t < NB2) cur[t] = atomicAdd(&gcur[t], cnt[t]);  // claim [cur, cur+cnt)
    __syncthreads();
    for (int e = e0 + t; e < e1; e += 1024) {
        int s = src[e], d = dst[e];
        int pd = atomicAdd(&cur[d >> 9], 1);
        dpart[pd] = s | ((d & 511) << 17);
        int ps = atomicAdd(&cur[NBK + (s >> 9)], 1);   // in [NE, 2*NE)
        spart[ps - NE] = (unsigned short)(s & 511);
    }
}

// ---------------- build pass 4: per-bucket degree count, offs, norms, CSR fill ----
__global__ __launch_bounds__(1024) void k_bucket(const int* __restrict__ dpart,
                                                 const unsigned short* __restrict__ spart,
                                                 const int* __restrict__ base,
                                                 int* __restrict__ offs,
                                                 int* __restrict__ csr,
                                                 float* __restrict__ ni,
                                                 float* __restrict__ no) {
    __shared__ int deg[512];
    __shared__ int cur[512];
    __shared__ int tmp[1024];
    int b = blockIdx.x;
    bool isDst = (b < NBK);
    int bb = isDst ? b : b - NBK;
    int start, end;
    if (isDst) {
        start = base[bb];
        end = base[bb + 1];
    } else {
        start = base[NBK + bb] - NE;
        end = base[NBK + bb + 1] - NE;
    }
    int t = threadIdx.x;
    if (t < 512) deg[t] = 0;
    __syncthreads();
    if (isDst) {
        for (int i = start + t; i < end; i += 1024)
            atomicAdd(&deg[(dpart[i] >> 17) & 511], 1);
    } else {
        for (int i = start + t; i < end; i += 1024)
            atomicAdd(&deg[spart[i]], 1);
    }
    __syncthreads();
    int vb = bb * 512;
    if (!isDst) {
        if (t < 512) {
            int v = vb + t;
            if (v < NN) no[v] = rsqrtf(fmaxf((float)deg[t], 1.0f));
        }
        return;
    }
    // exclusive scan of deg[512] via 1024-wide padded Hillis-Steele
    int a = (t < 512) ? deg[t] : 0;
    tmp[t] = a;
    __syncthreads();
    for (int off = 1; off < 1024; off <<= 1) {
        int v2 = (t >= off) ? tmp[t - off] : 0;
        __syncthreads();
        tmp[t] += v2;
        __syncthreads();
    }
    if (t < 512) {
        cur[t] = start + tmp[t] - a;
        int v = vb + t;
        if (v < NN) {
            offs[v] = cur[t];
            ni[v] = rsqrtf(fmaxf((float)a, 1.0f));
        }
    }
    if (b == NBK - 1 && t == 0) offs[NN] = NE;
    __syncthreads();
    for (int i = start + t; i < end; i += 1024) {
        int pk = dpart[i];
        int p = atomicAdd(&cur[(pk >> 17) & 511], 1);
        csr[p] = pk & 0x1FFFF;
    }
}

// ---------------- MFMA GEMM: Zh = no[row] * (A @ W), fp16 in, fp32 acc, fp16 out ----
template <typename TA>
__global__ __launch_bounds__(256) void k_gemm_mfma(const TA* __restrict__ A,
                                                   const _Float16* __restrict__ Bt,
                                                   const float* __restrict__ no,
                                                   _Float16* __restrict__ Zh,
                                                   int nrows) {
    __shared__ _Float16 Bs[128 * 136];  // 34 KB; B staging, then C staging
    int tid = threadIdx.x;
    {
        const h8* B8 = (const h8*)Bt;
        h8* Bs8 = (h8*)Bs;
        for (int i = tid; i < 2048; i += 256) {
            int n = i >> 4, c = i & 15;
            Bs8[n * 17 + c] = B8[i];
        }
    }

    int wave = tid >> 6;
    int lane = tid & 63;
    int m16 = lane & 15;
    int quad = lane >> 4;
    int rowbase = blockIdx.x * 64 + wave * 16;
    int row = rowbase + m16;
    bool valid = row < nrows;

    h8 afrag[4];
    if (valid) {
        if constexpr (sizeof(TA) == 2) {
            const h8* Arow = (const h8*)(A + (size_t)row * 128);
#pragma unroll
            for (int kk = 0; kk < 4; kk++) afrag[kk] = Arow[kk * 4 + quad];
        } else {
            const float4* Arow = (const float4*)(A + (size_t)row * 128);
#pragma unroll
            for (int kk = 0; kk < 4; kk++) {
                float4 lo = Arow[kk * 8 + quad * 2];
                float4 hi = Arow[kk * 8 + quad * 2 + 1];
                h8 a;
                a[0] = (_Float16)lo.x; a[1] = (_Float16)lo.y;
                a[2] = (_Float16)lo.z; a[3] = (_Float16)lo.w;
                a[4] = (_Float16)hi.x; a[5] = (_Float16)hi.y;
                a[6] = (_Float16)hi.z; a[7] = (_Float16)hi.w;
                afrag[kk] = a;
            }
        }
    } else {
#pragma unroll
        for (int kk = 0; kk < 4; kk++) {
            h8 a;
#pragma unroll
            for (int j = 0; j < 8; j++) a[j] = (_Float16)0.f;
            afrag[kk] = a;
        }
    }

    __syncthreads();

    f32x4 acc[8];
#pragma unroll
    for (int nt = 0; nt < 8; nt++) acc[nt] = (f32x4){0.f, 0.f, 0.f, 0.f};

    const h8* Bs8 = (const h8*)Bs;
#pragma unroll
    for (int nt = 0; nt < 8; nt++) {
        const h8* Bp = Bs8 + (size_t)(nt * 16 + m16) * 17;
#pragma unroll
        for (int kk = 0; kk < 4; kk++) {
            acc[nt] = __builtin_amdgcn_mfma_f32_16x16x32_f16(afrag[kk], Bp[kk * 4 + quad],
                                                             acc[nt], 0, 0, 0);
        }
    }

    // C/D layout: col = lane&15, row = quad*4 + reg  [m89-verified]
    float nor[4];
#pragma unroll
    for (int r = 0; r < 4; r++) {
        int grow = rowbase + quad * 4 + r;
        nor[r] = (grow < nrows) ? no[grow] : 0.f;
    }

    __syncthreads();  // all waves done reading Bs; reuse as C staging
    {
        int lr0 = wave * 16 + quad * 4;
#pragma unroll
        for (int nt = 0; nt < 8; nt++) {
#pragma unroll
            for (int r = 0; r < 4; r++) {
                Bs[(size_t)(lr0 + r) * 136 + nt * 16 + m16] =
                    (_Float16)(acc[nt][r] * nor[r]);
            }
        }
    }
    __syncthreads();

    int blockrow0 = blockIdx.x * 64;
    for (int i = tid; i < 1024; i += 256) {
        int r = i >> 4, cch = i & 15;
        int grow = blockrow0 + r;
        if (grow < nrows) {
            h8 val = *(const h8*)&Bs[(size_t)r * 136 + cch * 8];
            *(h8*)&Zh[(size_t)grow * 128 + cch * 8] = val;
        }
    }
}

// ---------------- aggregation: h'[v] = relu(ni[v]*sum_u zh[u] + b), fp16 out ----------
// R0 structure (measured floor: 59 us): 16 nodes/block, 16 lanes/node, 4-edge
// batches, no barriers. FETCH 178 MB = per-XCD compulsory coverage through the
// fabric at ~3.5 TB/s (8 x ~440 GB/s links) — pinned; keep pure (fusion hurt 3x).
__global__ __launch_bounds__(256) void k_agg(const h8* __restrict__ Zh,
                                             const int* __restrict__ offs,
                                             const int* __restrict__ csr,
                                             const float* __restrict__ ni,
                                             const float* __restrict__ b,
                                             h8* __restrict__ H16) {
    int v = blockIdx.x * 16 + (threadIdx.x >> 4);
    int c = threadIdx.x & 15;
    int s = offs[v];
    int e = offs[v + 1];
    float a0[8], a1[8];
#pragma unroll
    for (int j = 0; j < 8; j++) { a0[j] = 0.f; a1[j] = 0.f; }
    int i = s;
    for (; i + 4 <= e; i += 4) {
        int u0 = csr[i];
        int u1 = csr[i + 1];
        int u2 = csr[i + 2];
        int u3 = csr[i + 3];
        h8 z0 = Zh[(size_t)u0 * 16 + c];
        h8 z1 = Zh[(size_t)u1 * 16 + c];
        h8 z2 = Zh[(size_t)u2 * 16 + c];
        h8 z3 = Zh[(size_t)u3 * 16 + c];
#pragma unroll
        for (int j = 0; j < 8; j++) {
            a0[j] += (float)z0[j] + (float)z1[j];
            a1[j] += (float)z2[j] + (float)z3[j];
        }
    }
    for (; i < e; i++) {
        int u = csr[i];
        h8 z = Zh[(size_t)u * 16 + c];
#pragma unroll
        for (int j = 0; j < 8; j++) a0[j] += (float)z[j];
    }
    float niv = ni[v];
    const float* bb = b + c * 8;
    h8 r;
#pragma unroll
    for (int j = 0; j < 8; j++)
        r[j] = (_Float16)fmaxf((a0[j] + a1[j]) * niv + bb[j], 0.f);
    H16[(size_t)v * 16 + c] = r;
}

// ---------------- readout phase 1: per-graph partial sums -> gbuf (no atomics) ----
__global__ __launch_bounds__(256) void k_gsum(const h8* __restrict__ H8,
                                              const int* __restrict__ n2g,
                                              float* __restrict__ gbuf) {
    __shared__ float red[256 * 8];
    int gi = blockIdx.x >> 2;
    int part = blockIdx.x & 3;
    int t = threadIdx.x;
    int slot = t >> 4;
    int c = t & 15;

    int lo = 0, hi = NN;
    while (lo < hi) { int mid = (lo + hi) >> 1; if (n2g[mid] < gi) lo = mid + 1; else hi = mid; }
    int s = lo;
    hi = NN;
    while (lo < hi) { int mid = (lo + hi) >> 1; if (n2g[mid] < gi + 1) lo = mid + 1; else hi = mid; }
    int e = lo;

    float acc[8];
#pragma unroll
    for (int j = 0; j < 8; j++) acc[j] = 0.f;
    for (int v = s + part * 16 + slot; v < e; v += 64) {
        h8 z = H8[(size_t)v * 16 + c];
#pragma unroll
        for (int j = 0; j < 8; j++) acc[j] += (float)z[j];
    }
#pragma unroll
    for (int j = 0; j < 8; j++) red[t * 8 + j] = acc[j];
    __syncthreads();
    for (int off = 8; off >= 1; off >>= 1) {
        if (slot < off) {
#pragma unroll
            for (int j = 0; j < 8; j++)
                red[t * 8 + j] += red[(t + off * 16) * 8 + j];
        }
        __syncthreads();
    }
    if (slot == 0) {
#pragma unroll
        for (int j = 0; j < 8; j++)
            gbuf[((size_t)part * NG + gi) * 128 + c * 8 + j] = red[t * 8 + j];
    }
}

// ---------------- readout phase 2: sum 4 partials + MLP head ----------------
__global__ __launch_bounds__(128) void k_head(const float* __restrict__ gbuf,
                                              const float* __restrict__ Wm1,
                                              const float* __restrict__ bm1,
                                              const float* __restrict__ Wm2,
                                              const float* __restrict__ bm2,
                                              float* __restrict__ out) {
    __shared__ float gs[128];
    __shared__ float red2[128];
    int gi = blockIdx.x;
    int t = threadIdx.x;
    gs[t] = gbuf[(size_t)gi * 128 + t] +
            gbuf[((size_t)NG + gi) * 128 + t] +
            gbuf[((size_t)2 * NG + gi) * 128 + t] +
            gbuf[((size_t)3 * NG + gi) * 128 + t];
    __syncthreads();
    float a = bm1[t];
    for (int k = 0; k < 128; k++) a += gs[k] * Wm1[k * 128 + t];
    red2[t] = fmaxf(a, 0.f) * Wm2[t];
    __syncthreads();
    for (int s2 = 64; s2 > 0; s2 >>= 1) {
        if (t < s2) red2[t] += red2[t + s2];
        __syncthreads();
    }
    if (t == 0) out[gi] = red2[0] + bm2[0];
}

extern "C" void kernel_launch(void* const* d_in, const int* in_sizes, int n_in,
                              void* d_out, int out_size, void* d_ws, size_t ws_size,
                              hipStream_t stream) {
    const float* x   = (const float*)d_in[0];
    const int*   src = (const int*)d_in[1];
    const int*   dst = (const int*)d_in[2];
    const int*   n2g = (const int*)d_in[3];
    const float* W0  = (const float*)d_in[4];
    const float* b0  = (const float*)d_in[5];
    const float* W1  = (const float*)d_in[6];
    const float* b1  = (const float*)d_in[7];
    const float* W2  = (const float*)d_in[8];
    const float* b2  = (const float*)d_in[9];
    const float* Wm1 = (const float*)d_in[10];
    const float* bm1 = (const float*)d_in[11];
    const float* Wm2 = (const float*)d_in[12];
    const float* bm2 = (const float*)d_in[13];
    float* out = (float*)d_out;

    char* p = (char*)d_ws;
    auto carve = [&](size_t bytes) -> char* {
        char* r = p;
        p += (bytes + 255) & ~(size_t)255;
        return r;
    };
    _Float16* zh  = (_Float16*)carve((size_t)NN * HD * 2);
    _Float16* h16 = (_Float16*)carve((size_t)NN * HD * 2);
    _Float16* Bt  = (_Float16*)carve((size_t)3 * 128 * 128 * 2);
    float* no     = (float*)carve((size_t)NN * 4);
    float* ni     = (float*)carve((size_t)NN * 4);
    int*   offs   = (int*)carve((size_t)(NN + 1) * 4);
    int*   csr    = (int*)carve((size_t)NE * 4);
    int*   dpart  = (int*)carve((size_t)NE * 4);
    unsigned short* spart = (unsigned short*)carve((size_t)NE * 2);
    int*   Btot   = (int*)carve((size_t)NB2 * 4);
    int*   base   = (int*)carve((size_t)(NB2 + 1) * 4);
    int*   gcur   = (int*)carve((size_t)NB2 * 4);
    float* gbuf   = (float*)carve((size_t)4 * NG * 128 * 4);

    // graph build: flat 392-bucket counting sort with dynamic range claims.
    // (Global per-NODE atomics are ~25 G/s on this chip — R5 measured 130 us —
    //  but 245K low-contention per-BUCKET atomics are fine.)
    hipMemsetAsync(Btot, 0, (size_t)NB2 * 4, stream);
    k_count<<<NC2 + 48, 1024, 0, stream>>>(src, dst, Btot, W0, W1, W2, Bt);
    k_base<<<1, 512, 0, stream>>>(Btot, base, gcur);
    k_scatter2<<<NC2, 1024, 0, stream>>>(src, dst, gcur, dpart, spart);
    k_bucket<<<NB2, 1024, 0, stream>>>(dpart, spart, base, offs, csr, ni, no);

    int gemm_blocks = (NN + 63) / 64;  // 1563
    int agg_blocks  = NN / 16;         // 6250

    // layer 0 (fp32 input, converted in-kernel)
    k_gemm_mfma<float><<<gemm_blocks, 256, 0, stream>>>(x, Bt, no, zh, NN);
    k_agg<<<agg_blocks, 256, 0, stream>>>((const h8*)zh, offs, csr, ni, b0, (h8*)h16);
    // layer 1
    k_gemm_mfma<_Float16><<<gemm_blocks, 256, 0, stream>>>(h16, Bt + 16384, no, zh, NN);
    k_agg<<<agg_blocks, 256, 0, stream>>>((const h8*)zh, offs, csr, ni, b1, (h8*)h16);
    // layer 2
    k_gemm_mfma<_Float16><<<gemm_blocks, 256, 0, stream>>>(h16, Bt + 32768, no, zh, NN);
    k_agg<<<agg_blocks, 256, 0, stream>>>((const h8*)zh, offs, csr, ni, b2, (h8*)h16);

    // readout: atomic-free partial sums then head
    k_gsum<<<NG * 4, 256, 0, stream>>>((const h8*)h16, n2g, gbuf);
    k_head<<<NG, 128, 0, stream>>>(gbuf, Wm1, bm1, Wm2, bm2, out);
}

// Round 8
// 371.058 us; speedup vs baseline: 1.0907x; 1.0907x over previous
//
#include <hip/hip_runtime.h>

#define NN 100000
#define NE 1600000
#define NG 512
#define HD 128

#define NBK 196            // node buckets of 512: 196*512 = 100352 >= NN
#define CHUNK 5120         // edges per chunk
#define NC 313             // ceil(NE/CHUNK)
#define LH (2 * NBK * NC)  // 122696 histogram entries (dst part | src part)
#define BCAP 11264         // k_bucket LDS csr staging capacity (mean 8163, sigma~90)

typedef _Float16 h8 __attribute__((ext_vector_type(8)));
typedef float f32x4 __attribute__((ext_vector_type(4)));

// ---------------- pass A1: per-chunk bucket histograms + fused weight cast ----------
// blocks [0, NC): histogram chunks (1024 thr); blocks [NC, NC+48): cast W0..W2 -> Bt
__global__ __launch_bounds__(1024) void k_hist(const int* __restrict__ src,
                                               const int* __restrict__ dst,
                                               int* __restrict__ H,
                                               const float* __restrict__ W0,
                                               const float* __restrict__ W1,
                                               const float* __restrict__ W2,
                                               _Float16* __restrict__ Bt) {
    if (blockIdx.x >= NC) {
        int i = (blockIdx.x - NC) * 1024 + threadIdx.x;  // < 3*16384 = 48*1024
        int w = i >> 14;
        int rem = i & 16383;
        int n = rem >> 7;
        int k = rem & 127;
        const float* W = (w == 0) ? W0 : ((w == 1) ? W1 : W2);
        Bt[i] = (_Float16)W[k * 128 + n];
        return;
    }
    __shared__ int hd[NBK], hs[NBK];
    int c = blockIdx.x;
    for (int i = threadIdx.x; i < NBK; i += 1024) { hd[i] = 0; hs[i] = 0; }
    __syncthreads();
    int e0 = c * CHUNK;
    int e1 = e0 + CHUNK; if (e1 > NE) e1 = NE;
    for (int e = e0 + threadIdx.x; e < e1; e += 1024) {
        atomicAdd(&hd[dst[e] >> 9], 1);
        atomicAdd(&hs[src[e] >> 9], 1);
    }
    __syncthreads();
    for (int i = threadIdx.x; i < NBK; i += 1024) {
        H[i * NC + c] = hd[i];
        H[NBK * NC + i * NC + c] = hs[i];
    }
}

// ---------------- scan stage 1: per-256-block exclusive scan + block sums ----------------
__global__ __launch_bounds__(256) void k_scan1g(int* __restrict__ H,
                                                int* __restrict__ bsum, int L) {
    __shared__ int s[256];
    int i = blockIdx.x * 256 + threadIdx.x;
    int v = (i < L) ? H[i] : 0;
    s[threadIdx.x] = v;
    __syncthreads();
    for (int off = 1; off < 256; off <<= 1) {
        int t = (threadIdx.x >= off) ? s[threadIdx.x - off] : 0;
        __syncthreads();
        s[threadIdx.x] += t;
        __syncthreads();
    }
    if (i < L) H[i] = s[threadIdx.x] - v;
    if (threadIdx.x == 255) bsum[blockIdx.x] = s[255];
}

// ---------------- scan stage 2 (fused): every block re-scans bsum in LDS, then adds ----
__global__ __launch_bounds__(256) void k_scan3g(int* __restrict__ H,
                                                const int* __restrict__ bsum,
                                                int L, int nb) {
    __shared__ int sb[512];
    __shared__ int tmp2[256];
    int t = threadIdx.x;
    int b0 = (2 * t < nb) ? bsum[2 * t] : 0;
    int b1 = (2 * t + 1 < nb) ? bsum[2 * t + 1] : 0;
    int pair = b0 + b1;
    tmp2[t] = pair;
    __syncthreads();
    for (int off = 1; off < 256; off <<= 1) {
        int v2 = (t >= off) ? tmp2[t - off] : 0;
        __syncthreads();
        tmp2[t] += v2;
        __syncthreads();
    }
    int ex = tmp2[t] - pair;
    sb[2 * t] = ex;
    sb[2 * t + 1] = ex + b0;
    __syncthreads();
    int i = blockIdx.x * 256 + t;
    if (i < L) H[i] += sb[i >> 8];
}

// ---------------- pass A2: partition edges — LDS-reorder then COALESCED writes ----
// Scattered per-lane stores were the build bottleneck (64 lanes -> 64 lines/wave).
// Stage (value, bucket) in LDS ordered by bucket, then copy: consecutive lanes in
// a bucket run hit consecutive global addresses (~26-entry runs, ~6 lines/wave).
// dpart packed: src | (dst&511)<<17  (src < 2^17); spart: src&511 as ushort.
__global__ __launch_bounds__(1024) void k_scatter(const int* __restrict__ src,
                                                  const int* __restrict__ dst,
                                                  const int* __restrict__ H,
                                                  int* __restrict__ dpart,
                                                  unsigned short* __restrict__ spart) {
    __shared__ int valbuf[CHUNK];
    __shared__ unsigned short bidbuf[CHUNK];
    __shared__ int lcur[NBK], delta[NBK];
    __shared__ int tmp[256];
    int c = blockIdx.x;
    int t = threadIdx.x;
    int e0 = c * CHUNK;
    int e1 = e0 + CHUNK; if (e1 > NE) e1 = NE;
    int n = e1 - e0;

    // ================= dst phase =================
    for (int i = t; i < NBK; i += 1024) lcur[i] = 0;
    __syncthreads();
    for (int e = e0 + t; e < e1; e += 1024) atomicAdd(&lcur[dst[e] >> 9], 1);
    __syncthreads();
    {   // exclusive scan of lcur[196] (first 256 threads; all hit barriers)
        int v = (t < NBK) ? lcur[t] : 0;
        if (t < 256) tmp[t] = v;
        __syncthreads();
        for (int off = 1; off < 256; off <<= 1) {
            int add = (t < 256 && t >= off) ? tmp[t - off] : 0;
            __syncthreads();
            if (t < 256) tmp[t] += add;
            __syncthreads();
        }
        if (t < NBK) {
            int lbase = tmp[t] - v;
            lcur[t] = lbase;
            delta[t] = H[t * NC + c] - lbase;
        }
    }
    __syncthreads();
    for (int e = e0 + t; e < e1; e += 1024) {
        int s = src[e], d = dst[e];
        int b = d >> 9;
        int q = atomicAdd(&lcur[b], 1);
        valbuf[q] = s | ((d & 511) << 17);
        bidbuf[q] = (unsigned short)b;
    }
    __syncthreads();
    for (int i = t; i < n; i += 1024) dpart[delta[bidbuf[i]] + i] = valbuf[i];
    __syncthreads();

    // ================= src phase =================
    for (int i = t; i < NBK; i += 1024) lcur[i] = 0;
    __syncthreads();
    for (int e = e0 + t; e < e1; e += 1024) atomicAdd(&lcur[src[e] >> 9], 1);
    __syncthreads();
    {
        int v = (t < NBK) ? lcur[t] : 0;
        if (t < 256) tmp[t] = v;
        __syncthreads();
        for (int off = 1; off < 256; off <<= 1) {
            int add = (t < 256 && t >= off) ? tmp[t - off] : 0;
            __syncthreads();
            if (t < 256) tmp[t] += add;
            __syncthreads();
        }
        if (t < NBK) {
            int lbase = tmp[t] - v;
            lcur[t] = lbase;
            delta[t] = H[NBK * NC + t * NC + c] - NE - lbase;
        }
    }
    __syncthreads();
    for (int e = e0 + t; e < e1; e += 1024) {
        int s = src[e];
        int b = s >> 9;
        int q = atomicAdd(&lcur[b], 1);
        valbuf[q] = s & 511;
        bidbuf[q] = (unsigned short)b;
    }
    __syncthreads();
    for (int i = t; i < n; i += 1024)
        spart[delta[bidbuf[i]] + i] = (unsigned short)valbuf[i];
}

// ---------------- pass B: degree count, offs, norms, CSR fill (LDS-staged csr) ----
__global__ __launch_bounds__(1024) void k_bucket(const int* __restrict__ dpart,
                                                 const unsigned short* __restrict__ spart,
                                                 const int* __restrict__ H,
                                                 int* __restrict__ offs,
                                                 int* __restrict__ csr,
                                                 float* __restrict__ ni,
                                                 float* __restrict__ no) {
    __shared__ int deg[512];
    __shared__ int lcur[512];
    __shared__ int tmp[1024];
    __shared__ int csrbuf[BCAP];
    int b = blockIdx.x;
    bool isDst = (b < NBK);
    int bb = isDst ? b : b - NBK;
    int start, end;
    if (isDst) {
        start = H[bb * NC];
        end = (bb + 1 < NBK) ? H[(bb + 1) * NC] : NE;
    } else {
        start = H[NBK * NC + bb * NC] - NE;
        end = (bb + 1 < NBK) ? H[NBK * NC + (bb + 1) * NC] - NE : NE;
    }
    int t = threadIdx.x;
    if (t < 512) deg[t] = 0;
    __syncthreads();
    if (isDst) {
        for (int i = start + t; i < end; i += 1024)
            atomicAdd(&deg[(dpart[i] >> 17) & 511], 1);
    } else {
        for (int i = start + t; i < end; i += 1024)
            atomicAdd(&deg[spart[i]], 1);
    }
    __syncthreads();
    int vb = bb * 512;
    if (!isDst) {
        if (t < 512) {
            int v = vb + t;
            if (v < NN) no[v] = rsqrtf(fmaxf((float)deg[t], 1.0f));
        }
        return;
    }
    // exclusive scan of deg[512] via 1024-wide padded Hillis-Steele
    int a = (t < 512) ? deg[t] : 0;
    tmp[t] = a;
    __syncthreads();
    for (int off = 1; off < 1024; off <<= 1) {
        int v2 = (t >= off) ? tmp[t - off] : 0;
        __syncthreads();
        tmp[t] += v2;
        __syncthreads();
    }
    if (t < 512) {
        lcur[t] = tmp[t] - a;  // LOCAL base within [0, end-start)
        int v = vb + t;
        if (v < NN) {
            offs[v] = start + lcur[t];
            ni[v] = rsqrtf(fmaxf((float)a, 1.0f));
        }
    }
    if (b == NBK - 1 && t == 0) offs[NN] = NE;
    __syncthreads();
    int len = end - start;
    bool fits = (len <= BCAP);
    for (int i = start + t; i < end; i += 1024) {
        int pk = dpart[i];
        int q = atomicAdd(&lcur[(pk >> 17) & 511], 1);
        if (fits) csrbuf[q] = pk & 0x1FFFF;
        else      csr[start + q] = pk & 0x1FFFF;   // fallback (never expected)
    }
    __syncthreads();
    if (fits) {
        for (int i = t; i < len; i += 1024) csr[start + i] = csrbuf[i];
    }
}

// ---------------- MFMA GEMM: Zh = no[row] * (A @ W), fp16 in, fp32 acc, fp16 out ----
template <typename TA>
__global__ __launch_bounds__(256) void k_gemm_mfma(const TA* __restrict__ A,
                                                   const _Float16* __restrict__ Bt,
                                                   const float* __restrict__ no,
                                                   _Float16* __restrict__ Zh,
                                                   int nrows) {
    __shared__ _Float16 Bs[128 * 136];  // 34 KB; B staging, then C staging
    int tid = threadIdx.x;
    {
        const h8* B8 = (const h8*)Bt;
        h8* Bs8 = (h8*)Bs;
        for (int i = tid; i < 2048; i += 256) {
            int n = i >> 4, c = i & 15;
            Bs8[n * 17 + c] = B8[i];
        }
    }

    int wave = tid >> 6;
    int lane = tid & 63;
    int m16 = lane & 15;
    int quad = lane >> 4;
    int rowbase = blockIdx.x * 64 + wave * 16;
    int row = rowbase + m16;
    bool valid = row < nrows;

    h8 afrag[4];
    if (valid) {
        if constexpr (sizeof(TA) == 2) {
            const h8* Arow = (const h8*)(A + (size_t)row * 128);
#pragma unroll
            for (int kk = 0; kk < 4; kk++) afrag[kk] = Arow[kk * 4 + quad];
        } else {
            const float4* Arow = (const float4*)(A + (size_t)row * 128);
#pragma unroll
            for (int kk = 0; kk < 4; kk++) {
                float4 lo = Arow[kk * 8 + quad * 2];
                float4 hi = Arow[kk * 8 + quad * 2 + 1];
                h8 a;
                a[0] = (_Float16)lo.x; a[1] = (_Float16)lo.y;
                a[2] = (_Float16)lo.z; a[3] = (_Float16)lo.w;
                a[4] = (_Float16)hi.x; a[5] = (_Float16)hi.y;
                a[6] = (_Float16)hi.z; a[7] = (_Float16)hi.w;
                afrag[kk] = a;
            }
        }
    } else {
#pragma unroll
        for (int kk = 0; kk < 4; kk++) {
            h8 a;
#pragma unroll
            for (int j = 0; j < 8; j++) a[j] = (_Float16)0.f;
            afrag[kk] = a;
        }
    }

    __syncthreads();

    f32x4 acc[8];
#pragma unroll
    for (int nt = 0; nt < 8; nt++) acc[nt] = (f32x4){0.f, 0.f, 0.f, 0.f};

    const h8* Bs8 = (const h8*)Bs;
#pragma unroll
    for (int nt = 0; nt < 8; nt++) {
        const h8* Bp = Bs8 + (size_t)(nt * 16 + m16) * 17;
#pragma unroll
        for (int kk = 0; kk < 4; kk++) {
            acc[nt] = __builtin_amdgcn_mfma_f32_16x16x32_f16(afrag[kk], Bp[kk * 4 + quad],
                                                             acc[nt], 0, 0, 0);
        }
    }

    // C/D layout: col = lane&15, row = quad*4 + reg  [m89-verified]
    float nor[4];
#pragma unroll
    for (int r = 0; r < 4; r++) {
        int grow = rowbase + quad * 4 + r;
        nor[r] = (grow < nrows) ? no[grow] : 0.f;
    }

    __syncthreads();  // all waves done reading Bs; reuse as C staging
    {
        int lr0 = wave * 16 + quad * 4;
#pragma unroll
        for (int nt = 0; nt < 8; nt++) {
#pragma unroll
            for (int r = 0; r < 4; r++) {
                Bs[(size_t)(lr0 + r) * 136 + nt * 16 + m16] =
                    (_Float16)(acc[nt][r] * nor[r]);
            }
        }
    }
    __syncthreads();

    int blockrow0 = blockIdx.x * 64;
    for (int i = tid; i < 1024; i += 256) {
        int r = i >> 4, cch = i & 15;
        int grow = blockrow0 + r;
        if (grow < nrows) {
            h8 val = *(const h8*)&Bs[(size_t)r * 136 + cch * 8];
            *(h8*)&Zh[(size_t)grow * 128 + cch * 8] = val;
        }
    }
}

// ---------------- aggregation: h'[v] = relu(ni[v]*sum_u zh[u] + b), fp16 out ----------
// R0 structure (measured floor: ~59 us, 3.5 TB/s): 16 nodes/block, 16 lanes/node,
// 4-edge batches, no barriers. FETCH 178 MB = per-XCD compulsory coverage — pinned.
__global__ __launch_bounds__(256) void k_agg(const h8* __restrict__ Zh,
                                             const int* __restrict__ offs,
                                             const int* __restrict__ csr,
                                             const float* __restrict__ ni,
                                             const float* __restrict__ b,
                                             h8* __restrict__ H16) {
    int v = blockIdx.x * 16 + (threadIdx.x >> 4);
    int c = threadIdx.x & 15;
    int s = offs[v];
    int e = offs[v + 1];
    float a0[8], a1[8];
#pragma unroll
    for (int j = 0; j < 8; j++) { a0[j] = 0.f; a1[j] = 0.f; }
    int i = s;
    for (; i + 4 <= e; i += 4) {
        int u0 = csr[i];
        int u1 = csr[i + 1];
        int u2 = csr[i + 2];
        int u3 = csr[i + 3];
        h8 z0 = Zh[(size_t)u0 * 16 + c];
        h8 z1 = Zh[(size_t)u1 * 16 + c];
        h8 z2 = Zh[(size_t)u2 * 16 + c];
        h8 z3 = Zh[(size_t)u3 * 16 + c];
#pragma unroll
        for (int j = 0; j < 8; j++) {
            a0[j] += (float)z0[j] + (float)z1[j];
            a1[j] += (float)z2[j] + (float)z3[j];
        }
    }
    for (; i < e; i++) {
        int u = csr[i];
        h8 z = Zh[(size_t)u * 16 + c];
#pragma unroll
        for (int j = 0; j < 8; j++) a0[j] += (float)z[j];
    }
    float niv = ni[v];
    const float* bb = b + c * 8;
    h8 r;
#pragma unroll
    for (int j = 0; j < 8; j++)
        r[j] = (_Float16)fmaxf((a0[j] + a1[j]) * niv + bb[j], 0.f);
    H16[(size_t)v * 16 + c] = r;
}

// ---------------- readout phase 1: per-graph partial sums -> gbuf (no atomics) ----
__global__ __launch_bounds__(256) void k_gsum(const h8* __restrict__ H8,
                                              const int* __restrict__ n2g,
                                              float* __restrict__ gbuf) {
    __shared__ float red[256 * 8];
    int gi = blockIdx.x >> 2;
    int part = blockIdx.x & 3;
    int t = threadIdx.x;
    int slot = t >> 4;
    int c = t & 15;

    int lo = 0, hi = NN;
    while (lo < hi) { int mid = (lo + hi) >> 1; if (n2g[mid] < gi) lo = mid + 1; else hi = mid; }
    int s = lo;
    hi = NN;
    while (lo < hi) { int mid = (lo + hi) >> 1; if (n2g[mid] < gi + 1) lo = mid + 1; else hi = mid; }
    int e = lo;

    float acc[8];
#pragma unroll
    for (int j = 0; j < 8; j++) acc[j] = 0.f;
    for (int v = s + part * 16 + slot; v < e; v += 64) {
        h8 z = H8[(size_t)v * 16 + c];
#pragma unroll
        for (int j = 0; j < 8; j++) acc[j] += (float)z[j];
    }
#pragma unroll
    for (int j = 0; j < 8; j++) red[t * 8 + j] = acc[j];
    __syncthreads();
    for (int off = 8; off >= 1; off >>= 1) {
        if (slot < off) {
#pragma unroll
            for (int j = 0; j < 8; j++)
                red[t * 8 + j] += red[(t + off * 16) * 8 + j];
        }
        __syncthreads();
    }
    if (slot == 0) {
#pragma unroll
        for (int j = 0; j < 8; j++)
            gbuf[((size_t)part * NG + gi) * 128 + c * 8 + j] = red[t * 8 + j];
    }
}

// ---------------- readout phase 2: sum 4 partials + MLP head ----------------
__global__ __launch_bounds__(128) void k_head(const float* __restrict__ gbuf,
                                              const float* __restrict__ Wm1,
                                              const float* __restrict__ bm1,
                                              const float* __restrict__ Wm2,
                                              const float* __restrict__ bm2,
                                              float* __restrict__ out) {
    __shared__ float gs[128];
    __shared__ float red2[128];
    int gi = blockIdx.x;
    int t = threadIdx.x;
    gs[t] = gbuf[(size_t)gi * 128 + t] +
            gbuf[((size_t)NG + gi) * 128 + t] +
            gbuf[((size_t)2 * NG + gi) * 128 + t] +
            gbuf[((size_t)3 * NG + gi) * 128 + t];
    __syncthreads();
    float a = bm1[t];
    for (int k = 0; k < 128; k++) a += gs[k] * Wm1[k * 128 + t];
    red2[t] = fmaxf(a, 0.f) * Wm2[t];
    __syncthreads();
    for (int s2 = 64; s2 > 0; s2 >>= 1) {
        if (t < s2) red2[t] += red2[t + s2];
        __syncthreads();
    }
    if (t == 0) out[gi] = red2[0] + bm2[0];
}

extern "C" void kernel_launch(void* const* d_in, const int* in_sizes, int n_in,
                              void* d_out, int out_size, void* d_ws, size_t ws_size,
                              hipStream_t stream) {
    const float* x   = (const float*)d_in[0];
    const int*   src = (const int*)d_in[1];
    const int*   dst = (const int*)d_in[2];
    const int*   n2g = (const int*)d_in[3];
    const float* W0  = (const float*)d_in[4];
    const float* b0  = (const float*)d_in[5];
    const float* W1  = (const float*)d_in[6];
    const float* b1  = (const float*)d_in[7];
    const float* W2  = (const float*)d_in[8];
    const float* b2  = (const float*)d_in[9];
    const float* Wm1 = (const float*)d_in[10];
    const float* bm1 = (const float*)d_in[11];
    const float* Wm2 = (const float*)d_in[12];
    const float* bm2 = (const float*)d_in[13];
    float* out = (float*)d_out;

    char* p = (char*)d_ws;
    auto carve = [&](size_t bytes) -> char* {
        char* r = p;
        p += (bytes + 255) & ~(size_t)255;
        return r;
    };
    _Float16* zh  = (_Float16*)carve((size_t)NN * HD * 2);
    _Float16* h16 = (_Float16*)carve((size_t)NN * HD * 2);
    _Float16* Bt  = (_Float16*)carve((size_t)3 * 128 * 128 * 2);
    float* no     = (float*)carve((size_t)NN * 4);
    float* ni     = (float*)carve((size_t)NN * 4);
    int*   offs   = (int*)carve((size_t)(NN + 1) * 4);
    int*   csr    = (int*)carve((size_t)NE * 4);
    int*   Hh     = (int*)carve((size_t)LH * 4);
    int*   bsum   = (int*)carve((size_t)512 * 4);
    int*   dpart  = (int*)carve((size_t)NE * 4);
    unsigned short* spart = (unsigned short*)carve((size_t)NE * 2);
    float* gbuf   = (float*)carve((size_t)4 * NG * 128 * 4);

    // graph build: chunked LDS-atomic counting sort (R6 skeleton) with LDS-reordered
    // coalesced scatter/csr writes (scattered per-lane stores were the build cost).
    int scan_blocks = (LH + 255) / 256;  // 480 <= 512
    k_hist<<<NC + 48, 1024, 0, stream>>>(src, dst, Hh, W0, W1, W2, Bt);
    k_scan1g<<<scan_blocks, 256, 0, stream>>>(Hh, bsum, LH);
    k_scan3g<<<scan_blocks, 256, 0, stream>>>(Hh, bsum, LH, scan_blocks);
    k_scatter<<<NC, 1024, 0, stream>>>(src, dst, Hh, dpart, spart);
    k_bucket<<<2 * NBK, 1024, 0, stream>>>(dpart, spart, Hh, offs, csr, ni, no);

    int gemm_blocks = (NN + 63) / 64;  // 1563
    int agg_blocks  = NN / 16;         // 6250

    // layer 0 (fp32 input, converted in-kernel)
    k_gemm_mfma<float><<<gemm_blocks, 256, 0, stream>>>(x, Bt, no, zh, NN);
    k_agg<<<agg_blocks, 256, 0, stream>>>((const h8*)zh, offs, csr, ni, b0, (h8*)h16);
    // layer 1
    k_gemm_mfma<_Float16><<<gemm_blocks, 256, 0, stream>>>(h16, Bt + 16384, no, zh, NN);
    k_agg<<<agg_blocks, 256, 0, stream>>>((const h8*)zh, offs, csr, ni, b1, (h8*)h16);
    // layer 2
    k_gemm_mfma<_Float16><<<gemm_blocks, 256, 0, stream>>>(h16, Bt + 32768, no, zh, NN);
    k_agg<<<agg_blocks, 256, 0, stream>>>((const h8*)zh, offs, csr, ni, b2, (h8*)h16);

    // readout: atomic-free partial sums then head
    k_gsum<<<NG * 4, 256, 0, stream>>>((const h8*)h16, n2g, gbuf);
    k_head<<<NG, 128, 0, stream>>>(gbuf, Wm1, bm1, Wm2, bm2, out);
}